// Round 2
// baseline (388.870 us; speedup 1.0000x reference)
//
#include <hip/hip_runtime.h>

typedef __bf16 bf16;
typedef __bf16 bf16x8 __attribute__((ext_vector_type(8)));
typedef float f32x4 __attribute__((ext_vector_type(4)));

#define D_MODEL 1024
#define PROJ    256
#define SEQ     2048
#define BATCH   2
#define TOK     4096   // BATCH*SEQ
#define NH      16
#define DH      64
#define NEG_BIG (-1e30f)

// ---------------------------------------------------------------------------
// fp32 -> bf16 straight conversion (row-major preserved).
__global__ void cvt_kernel(const float* __restrict__ in, bf16* __restrict__ out, int n) {
    for (int i = blockIdx.x * blockDim.x + threadIdx.x; i < n;
         i += gridDim.x * blockDim.x)
        out[i] = (bf16)in[i];
}

// fp32 W[K][N] -> bf16 Wt[N][K] (n-major), so B-fragment loads are contiguous.
__global__ void transpose_cvt_kernel(const float* __restrict__ in, bf16* __restrict__ out,
                                     int K, int N) {
    int total = K * N;
    for (int i = blockIdx.x * blockDim.x + threadIdx.x; i < total;
         i += gridDim.x * blockDim.x) {
        int n = i / K;
        int k = i - n * K;
        out[i] = (bf16)in[k * N + n];
    }
}

// ---------------------------------------------------------------------------
// C_ln[4096][256] = LayerNorm_rowwise(A[4096][1024] @ W) with Wt[256][1024] n-major.
// Block: 16 rows x 256 cols, 4 waves (each wave owns 64 cols).
__global__ __launch_bounds__(256) void gemm_ln_kernel(
    const bf16* __restrict__ A, const bf16* __restrict__ Wt,
    const float* __restrict__ gamma, const float* __restrict__ beta,
    bf16* __restrict__ out) {
    const int K = 1024;
    const int m0 = blockIdx.x * 16;
    const int wv = threadIdx.x >> 6;
    const int lane = threadIdx.x & 63;
    const int g = lane >> 4;        // quad
    const int ln16 = lane & 15;
    const int ncol0 = wv * 64;

    f32x4 acc[4] = {};
    const bf16* arow = A + (size_t)(m0 + ln16) * K + g * 8;
    for (int k0 = 0; k0 < K; k0 += 32) {
        bf16x8 a = *(const bf16x8*)(arow + k0);
#pragma unroll
        for (int t = 0; t < 4; ++t) {
            const bf16* bp = Wt + (size_t)(ncol0 + 16 * t + ln16) * K + k0 + g * 8;
            bf16x8 b = *(const bf16x8*)bp;
            acc[t] = __builtin_amdgcn_mfma_f32_16x16x32_bf16(a, b, acc[t], 0, 0, 0);
        }
    }

    // Row reduction for LN: lane holds (row=g*4+r, col=ncol0+16t+ln16).
    float s1[4], s2[4];
#pragma unroll
    for (int r = 0; r < 4; ++r) {
        float a = 0.f, b = 0.f;
#pragma unroll
        for (int t = 0; t < 4; ++t) { float v = acc[t][r]; a += v; b += v * v; }
        s1[r] = a; s2[r] = b;
    }
#pragma unroll
    for (int mask = 1; mask < 16; mask <<= 1) {
#pragma unroll
        for (int r = 0; r < 4; ++r) {
            s1[r] += __shfl_xor(s1[r], mask);
            s2[r] += __shfl_xor(s2[r], mask);
        }
    }
    __shared__ float red1[4][16];
    __shared__ float red2[4][16];
    if (ln16 == 0) {
#pragma unroll
        for (int r = 0; r < 4; ++r) {
            red1[wv][g * 4 + r] = s1[r];
            red2[wv][g * 4 + r] = s2[r];
        }
    }
    __syncthreads();
#pragma unroll
    for (int r = 0; r < 4; ++r) {
        int row = g * 4 + r;
        float t1 = red1[0][row] + red1[1][row] + red1[2][row] + red1[3][row];
        float t2 = red2[0][row] + red2[1][row] + red2[2][row] + red2[3][row];
        float mu = t1 * (1.0f / 256.0f);
        float var = t2 * (1.0f / 256.0f) - mu * mu;
        float rs = rsqrtf(var + 1e-5f);
#pragma unroll
        for (int t = 0; t < 4; ++t) {
            int col = ncol0 + 16 * t + ln16;
            float v = (acc[t][r] - mu) * rs * gamma[col] + beta[col];
            out[(size_t)(m0 + row) * PROJ + col] = (bf16)v;
        }
    }
}

// ---------------------------------------------------------------------------
// Generic C[M][N] = A[M][K] @ B where Bt[N][K] is n-major. bf16 in, fp32 acc,
// OutT out (bf16 for internal tensors, float for the final output).
template <typename OutT>
__global__ __launch_bounds__(256) void gemm_kernel(
    const bf16* __restrict__ A, const bf16* __restrict__ Bt,
    OutT* __restrict__ C, int M, int N, int K) {
    const int m0 = blockIdx.x * 32;
    const int n0 = blockIdx.y * 256 + (threadIdx.x >> 6) * 64;
    const int lane = threadIdx.x & 63;
    const int g = lane >> 4;
    const int ln16 = lane & 15;

    f32x4 acc[2][4] = {};
    const bf16* a0 = A + (size_t)(m0 + ln16) * K + g * 8;
    const bf16* a1 = a0 + (size_t)16 * K;
    for (int k0 = 0; k0 < K; k0 += 32) {
        bf16x8 A0 = *(const bf16x8*)(a0 + k0);
        bf16x8 A1 = *(const bf16x8*)(a1 + k0);
#pragma unroll
        for (int t = 0; t < 4; ++t) {
            const bf16* bp = Bt + (size_t)(n0 + 16 * t + ln16) * K + k0 + g * 8;
            bf16x8 b = *(const bf16x8*)bp;
            acc[0][t] = __builtin_amdgcn_mfma_f32_16x16x32_bf16(A0, b, acc[0][t], 0, 0, 0);
            acc[1][t] = __builtin_amdgcn_mfma_f32_16x16x32_bf16(A1, b, acc[1][t], 0, 0, 0);
        }
    }
#pragma unroll
    for (int s = 0; s < 2; ++s)
#pragma unroll
        for (int t = 0; t < 4; ++t)
#pragma unroll
            for (int r = 0; r < 4; ++r) {
                int row = m0 + 16 * s + g * 4 + r;
                int col = n0 + 16 * t + ln16;
                C[(size_t)row * N + col] = (OutT)acc[s][t][r];
            }
}

// ---------------------------------------------------------------------------
// Flash-style causal attention. One wave = one 16-query tile of one (b,h).
// Q[4096][1024], KV[4096][2048] (cols 0..1023 = K, 1024..2047 = V).
__global__ __launch_bounds__(256) void attn_kernel(
    const bf16* __restrict__ Q, const bf16* __restrict__ KV,
    bf16* __restrict__ O) {
    __shared__ alignas(16) unsigned short pbuf[4][16 * 32];  // per-wave P tile (bf16 bits)

    const int wv = threadIdx.x >> 6;
    const int lane = threadIdx.x & 63;
    const int g = lane >> 4;
    const int ln16 = lane & 15;

    const int wid = blockIdx.x * 4 + wv;      // 0..4095
    const int h = wid & 15;
    const int qt = (wid >> 4) & 127;
    const int b = wid >> 11;
    const int qb = qt * 16;
    const size_t tb = (size_t)b * SEQ;

    const bf16* qp = Q + (tb + qb + ln16) * D_MODEL + h * DH + g * 8;
    bf16x8 aq0 = *(const bf16x8*)qp;
    bf16x8 aq1 = *(const bf16x8*)(qp + 32);

    f32x4 o[4] = {};
    float mi[4], li[4];
#pragma unroll
    for (int r = 0; r < 4; ++r) { mi[r] = NEG_BIG; li[r] = 0.f; }

    const int ntiles = (qb + 15) / 32 + 1;
    unsigned short* pb = &pbuf[wv][0];

    for (int kt = 0; kt < ntiles; ++kt) {
        const int k0 = kt * 32;
        f32x4 sc[2];
#pragma unroll
        for (int c = 0; c < 2; ++c) {
            const bf16* kp = KV + (tb + k0 + 16 * c + ln16) * (2 * D_MODEL) + h * DH + g * 8;
            bf16x8 b0 = *(const bf16x8*)kp;
            bf16x8 b1 = *(const bf16x8*)(kp + 32);
            f32x4 z = {};
            z = __builtin_amdgcn_mfma_f32_16x16x32_bf16(aq0, b0, z, 0, 0, 0);
            z = __builtin_amdgcn_mfma_f32_16x16x32_bf16(aq1, b1, z, 0, 0, 0);
            sc[c] = z;
        }
        // scale + NaN-launder + causal mask; per-row tile max
        float mx[4];
#pragma unroll
        for (int r = 0; r < 4; ++r) {
            int qrow = qb + g * 4 + r;
#pragma unroll
            for (int c = 0; c < 2; ++c) {
                int col = k0 + 16 * c + ln16;
                float v = sc[c][r] * 0.125f;
                v = fminf(fmaxf(v, NEG_BIG), 1e30f);   // fmaxf(NaN,x)=x: launders NaN
                if (col > qrow) v = NEG_BIG;
                sc[c][r] = v;
            }
            mx[r] = fmaxf(sc[0][r], sc[1][r]);
        }
#pragma unroll
        for (int mask = 1; mask < 16; mask <<= 1)
#pragma unroll
            for (int r = 0; r < 4; ++r) mx[r] = fmaxf(mx[r], __shfl_xor(mx[r], mask));

        float alpha[4], ssum[4];
#pragma unroll
        for (int r = 0; r < 4; ++r) {
            float mnew = fmaxf(mi[r], mx[r]);
            alpha[r] = __expf(mi[r] - mnew);
            mi[r] = mnew;
            float p0 = __expf(sc[0][r] - mnew);
            float p1 = __expf(sc[1][r] - mnew);
            sc[0][r] = p0; sc[1][r] = p1;
            ssum[r] = p0 + p1;
        }
#pragma unroll
        for (int mask = 1; mask < 16; mask <<= 1)
#pragma unroll
            for (int r = 0; r < 4; ++r) ssum[r] += __shfl_xor(ssum[r], mask);
#pragma unroll
        for (int r = 0; r < 4; ++r) li[r] = li[r] * alpha[r] + ssum[r];
#pragma unroll
        for (int t = 0; t < 4; ++t)
#pragma unroll
            for (int r = 0; r < 4; ++r) o[t][r] *= alpha[r];

        // P (C-layout) -> LDS -> A-layout fragment
#pragma unroll
        for (int c = 0; c < 2; ++c)
#pragma unroll
            for (int r = 0; r < 4; ++r) {
                bf16 pv = (bf16)sc[c][r];
                pb[(g * 4 + r) * 32 + 16 * c + ln16] =
                    __builtin_bit_cast(unsigned short, pv);
            }
        __asm__ volatile("s_waitcnt lgkmcnt(0)" ::: "memory");
        bf16x8 pf = *(const bf16x8*)(pb + ln16 * 32 + g * 8);

        // V B-fragments (gathered) + PV
        const bf16* vbase = KV + (tb + k0 + g * 8) * (2 * D_MODEL) + D_MODEL + h * DH + ln16;
#pragma unroll
        for (int t = 0; t < 4; ++t) {
            bf16x8 bv;
#pragma unroll
            for (int j = 0; j < 8; ++j) bv[j] = vbase[(size_t)j * (2 * D_MODEL) + 16 * t];
            o[t] = __builtin_amdgcn_mfma_f32_16x16x32_bf16(pf, bv, o[t], 0, 0, 0);
        }
    }

#pragma unroll
    for (int t = 0; t < 4; ++t)
#pragma unroll
        for (int r = 0; r < 4; ++r) {
            int qrow = qb + g * 4 + r;
            float v = o[t][r] / li[r];
            O[(tb + qrow) * D_MODEL + h * DH + 16 * t + ln16] = (bf16)v;
        }
}

// ---------------------------------------------------------------------------
extern "C" void kernel_launch(void* const* d_in, const int* in_sizes, int n_in,
                              void* d_out, int out_size, void* d_ws, size_t ws_size,
                              hipStream_t stream) {
    const float* x     = (const float*)d_in[0];   // [2][2048][1024]
    const float* W_dq  = (const float*)d_in[1];   // [1024][256]
    const float* W_uq  = (const float*)d_in[2];   // [256][1024]
    const float* q_g   = (const float*)d_in[3];
    const float* q_b   = (const float*)d_in[4];
    const float* W_dkv = (const float*)d_in[5];   // [1024][256]
    const float* W_ukv = (const float*)d_in[6];   // [256][2048]
    const float* kv_g  = (const float*)d_in[7];
    const float* kv_b  = (const float*)d_in[8];
    const float* W_o   = (const float*)d_in[9];   // [1024][1024] (n-major for @W_o.T)

    char* ws = (char*)d_ws;
    size_t off = 0;
    bf16* x16    = (bf16*)(ws + off); off += (size_t)TOK * D_MODEL * 2;         // 8MB
    bf16* Wo16   = (bf16*)(ws + off); off += (size_t)D_MODEL * D_MODEL * 2;     // 2MB
    bf16* Wt_dq  = (bf16*)(ws + off); off += (size_t)PROJ * D_MODEL * 2;
    bf16* Wt_dkv = (bf16*)(ws + off); off += (size_t)PROJ * D_MODEL * 2;
    bf16* Wt_uq  = (bf16*)(ws + off); off += (size_t)D_MODEL * PROJ * 2;
    bf16* Wt_ukv = (bf16*)(ws + off); off += (size_t)(2 * D_MODEL) * PROJ * 2;
    bf16* cq     = (bf16*)(ws + off); off += (size_t)TOK * PROJ * 2;
    bf16* ckv    = (bf16*)(ws + off); off += (size_t)TOK * PROJ * 2;
    bf16* Qb     = (bf16*)(ws + off); off += (size_t)TOK * D_MODEL * 2;
    bf16* KVb    = (bf16*)(ws + off); off += (size_t)TOK * 2 * D_MODEL * 2;
    bf16* AT     = (bf16*)(ws + off); off += (size_t)TOK * D_MODEL * 2;

    // conversions + weight transposes to n-major bf16
    cvt_kernel<<<2048, 256, 0, stream>>>(x, x16, TOK * D_MODEL);
    cvt_kernel<<<1024, 256, 0, stream>>>(W_o, Wo16, D_MODEL * D_MODEL);
    transpose_cvt_kernel<<<512, 256, 0, stream>>>(W_dq,  Wt_dq,  D_MODEL, PROJ);
    transpose_cvt_kernel<<<512, 256, 0, stream>>>(W_dkv, Wt_dkv, D_MODEL, PROJ);
    transpose_cvt_kernel<<<512, 256, 0, stream>>>(W_uq,  Wt_uq,  PROJ, D_MODEL);
    transpose_cvt_kernel<<<1024, 256, 0, stream>>>(W_ukv, Wt_ukv, PROJ, 2 * D_MODEL);

    // cq = LN(x @ W_dq), ckv = LN(x @ W_dkv)
    gemm_ln_kernel<<<TOK / 16, 256, 0, stream>>>(x16, Wt_dq,  q_g,  q_b,  cq);
    gemm_ln_kernel<<<TOK / 16, 256, 0, stream>>>(x16, Wt_dkv, kv_g, kv_b, ckv);

    // Q = cq @ W_uq ; KV = ckv @ W_ukv
    gemm_kernel<bf16><<<dim3(TOK / 32, D_MODEL / 256), 256, 0, stream>>>(
        cq, Wt_uq, Qb, TOK, D_MODEL, PROJ);
    gemm_kernel<bf16><<<dim3(TOK / 32, (2 * D_MODEL) / 256), 256, 0, stream>>>(
        ckv, Wt_ukv, KVb, TOK, 2 * D_MODEL, PROJ);

    // attention
    attn_kernel<<<(BATCH * NH * (SEQ / 16)) / 4, 256, 0, stream>>>(Qb, KVb, AT);

    // out = attn @ W_o^T  (fp32 output)
    gemm_kernel<float><<<dim3(TOK / 32, D_MODEL / 256), 256, 0, stream>>>(
        AT, Wo16, (float*)d_out, TOK, D_MODEL, D_MODEL);
}

// Round 3
// 388.461 us; speedup vs baseline: 1.0011x; 1.0011x over previous
//
#include <hip/hip_runtime.h>

typedef __bf16 bf16;
typedef __bf16 bf16x4 __attribute__((ext_vector_type(4)));
typedef __bf16 bf16x8 __attribute__((ext_vector_type(8)));
typedef float f32x4 __attribute__((ext_vector_type(4)));

#define D_MODEL 1024
#define PROJ    256
#define SEQ     2048
#define BATCH   2
#define TOK     4096   // BATCH*SEQ
#define NH      16
#define DH      64
#define NEG_BIG (-1e30f)
#define PSTR    72     // LDS P-tile stride (elements): 2-way bank aliasing only

// ---------------------------------------------------------------------------
__global__ void cvt_kernel(const float* __restrict__ in, bf16* __restrict__ out, int n) {
    for (int i = blockIdx.x * blockDim.x + threadIdx.x; i < n;
         i += gridDim.x * blockDim.x)
        out[i] = (bf16)in[i];
}

// fp32 W[K][N] -> bf16 Wt[N][K] (n-major)
__global__ void transpose_cvt_kernel(const float* __restrict__ in, bf16* __restrict__ out,
                                     int K, int N) {
    int total = K * N;
    for (int i = blockIdx.x * blockDim.x + threadIdx.x; i < total;
         i += gridDim.x * blockDim.x) {
        int n = i / K;
        int k = i - n * K;
        out[i] = (bf16)in[k * N + n];
    }
}

// ---------------------------------------------------------------------------
// C_ln[4096][256] = LayerNorm_rowwise(A[4096][1024] @ W), Wt n-major.
__global__ __launch_bounds__(256) void gemm_ln_kernel(
    const bf16* __restrict__ A, const bf16* __restrict__ Wt,
    const float* __restrict__ gamma, const float* __restrict__ beta,
    bf16* __restrict__ out) {
    const int K = 1024;
    const int m0 = blockIdx.x * 16;
    const int wv = threadIdx.x >> 6;
    const int lane = threadIdx.x & 63;
    const int g = lane >> 4;
    const int ln16 = lane & 15;
    const int ncol0 = wv * 64;

    f32x4 acc[4] = {};
    const bf16* arow = A + (size_t)(m0 + ln16) * K + g * 8;
    for (int k0 = 0; k0 < K; k0 += 32) {
        bf16x8 a = *(const bf16x8*)(arow + k0);
#pragma unroll
        for (int t = 0; t < 4; ++t) {
            const bf16* bp = Wt + (size_t)(ncol0 + 16 * t + ln16) * K + k0 + g * 8;
            bf16x8 b = *(const bf16x8*)bp;
            acc[t] = __builtin_amdgcn_mfma_f32_16x16x32_bf16(a, b, acc[t], 0, 0, 0);
        }
    }

    float s1[4], s2[4];
#pragma unroll
    for (int r = 0; r < 4; ++r) {
        float a = 0.f, b = 0.f;
#pragma unroll
        for (int t = 0; t < 4; ++t) { float v = acc[t][r]; a += v; b += v * v; }
        s1[r] = a; s2[r] = b;
    }
#pragma unroll
    for (int mask = 1; mask < 16; mask <<= 1) {
#pragma unroll
        for (int r = 0; r < 4; ++r) {
            s1[r] += __shfl_xor(s1[r], mask);
            s2[r] += __shfl_xor(s2[r], mask);
        }
    }
    __shared__ float red1[4][16];
    __shared__ float red2[4][16];
    if (ln16 == 0) {
#pragma unroll
        for (int r = 0; r < 4; ++r) {
            red1[wv][g * 4 + r] = s1[r];
            red2[wv][g * 4 + r] = s2[r];
        }
    }
    __syncthreads();
#pragma unroll
    for (int r = 0; r < 4; ++r) {
        int row = g * 4 + r;
        float t1 = red1[0][row] + red1[1][row] + red1[2][row] + red1[3][row];
        float t2 = red2[0][row] + red2[1][row] + red2[2][row] + red2[3][row];
        float mu = t1 * (1.0f / 256.0f);
        float var = t2 * (1.0f / 256.0f) - mu * mu;
        float rs = rsqrtf(var + 1e-5f);
#pragma unroll
        for (int t = 0; t < 4; ++t) {
            int col = ncol0 + 16 * t + ln16;
            float v = (acc[t][r] - mu) * rs * gamma[col] + beta[col];
            out[(size_t)(m0 + row) * PROJ + col] = (bf16)v;
        }
    }
}

// ---------------------------------------------------------------------------
// Generic MFMA GEMM, A[M][K] row-major bf16, Bt[N][K] n-major bf16, fp32 acc.
// MODE 0: C[M][N] row-major, OutT.
// MODE 1: C = head-major bf16 [b*16+h][2048][64]   (Q up-proj)
// MODE 2: cols<1024 -> C = Kh head-major; cols>=1024 -> C2 = Vt [bh][64][2048]
template <int MODE, typename OutT>
__global__ __launch_bounds__(256) void gemm_kernel(
    const bf16* __restrict__ A, const bf16* __restrict__ Bt,
    OutT* __restrict__ C, bf16* __restrict__ C2, int M, int N, int K) {
    const int m0 = blockIdx.x * 32;
    const int n0 = blockIdx.y * 256 + (threadIdx.x >> 6) * 64;
    const int lane = threadIdx.x & 63;
    const int g = lane >> 4;
    const int ln16 = lane & 15;

    f32x4 acc[2][4] = {};
    const bf16* a0 = A + (size_t)(m0 + ln16) * K + g * 8;
    const bf16* a1 = a0 + (size_t)16 * K;
    for (int k0 = 0; k0 < K; k0 += 32) {
        bf16x8 A0 = *(const bf16x8*)(a0 + k0);
        bf16x8 A1 = *(const bf16x8*)(a1 + k0);
#pragma unroll
        for (int t = 0; t < 4; ++t) {
            const bf16* bp = Bt + (size_t)(n0 + 16 * t + ln16) * K + k0 + g * 8;
            bf16x8 b = *(const bf16x8*)bp;
            acc[0][t] = __builtin_amdgcn_mfma_f32_16x16x32_bf16(A0, b, acc[0][t], 0, 0, 0);
            acc[1][t] = __builtin_amdgcn_mfma_f32_16x16x32_bf16(A1, b, acc[1][t], 0, 0, 0);
        }
    }
#pragma unroll
    for (int s = 0; s < 2; ++s)
#pragma unroll
        for (int t = 0; t < 4; ++t) {
            const int col = n0 + 16 * t + ln16;
            const int tok0 = m0 + 16 * s + g * 4;      // r gives consecutive tokens
            if (MODE == 2 && col >= 1024) {
                // V part -> Vt[bh][d][s], 4 consecutive tokens packed per store
                int cc = col - 1024;
                int h = cc >> 6, d = cc & 63;
                int b = tok0 >> 11, sq = tok0 & 2047;
                bf16x4 pk;
#pragma unroll
                for (int r = 0; r < 4; ++r) pk[r] = (bf16)acc[s][t][r];
                *(bf16x4*)(C2 + ((size_t)((b * 16 + h) * 64 + d) * SEQ + sq)) = pk;
            } else {
#pragma unroll
                for (int r = 0; r < 4; ++r) {
                    int row = tok0 + r;
                    float v = acc[s][t][r];
                    if (MODE == 0) {
                        C[(size_t)row * N + col] = (OutT)v;
                    } else {
                        int h = col >> 6, d = col & 63;
                        int b = row >> 11, sq = row & 2047;
                        C[((size_t)((b * 16 + h) * 2048 + sq)) * 64 + d] = (OutT)v;
                    }
                }
            }
        }
}

// ---------------------------------------------------------------------------
// Flash attention, one wave = 16 q-rows, k-tile = 64.
// Qh/Kh: [bh][2048][64], Vt: [bh][64][2048], O: token-major [4096][1024].
template <bool MASKED>
__device__ __forceinline__ void attn_tile(
    int k0, int qb, int g, int ln16,
    bf16x8 aq0, bf16x8 aq1,
    const bf16* __restrict__ Kbh, const bf16* __restrict__ Vbh,
    unsigned short* __restrict__ pb,
    float* mi, float* li, f32x4* o) {
    f32x4 sc[4];
#pragma unroll
    for (int c = 0; c < 4; ++c) {
        const bf16* kp = Kbh + (size_t)(k0 + 16 * c + ln16) * DH + g * 8;
        bf16x8 b0 = *(const bf16x8*)kp;
        bf16x8 b1 = *(const bf16x8*)(kp + 32);
        f32x4 z = {};
        z = __builtin_amdgcn_mfma_f32_16x16x32_bf16(aq0, b0, z, 0, 0, 0);
        z = __builtin_amdgcn_mfma_f32_16x16x32_bf16(aq1, b1, z, 0, 0, 0);
        sc[c] = z;
    }
    float mx[4];
#pragma unroll
    for (int r = 0; r < 4; ++r) {
#pragma unroll
        for (int c = 0; c < 4; ++c) {
            float v = sc[c][r] * 0.125f;
            if (MASKED) {
                int qrow = qb + g * 4 + r;
                int col = k0 + 16 * c + ln16;
                if (col > qrow) v = NEG_BIG;
            }
            sc[c][r] = v;
        }
        mx[r] = fmaxf(fmaxf(sc[0][r], sc[1][r]), fmaxf(sc[2][r], sc[3][r]));
    }
#pragma unroll
    for (int mask = 1; mask < 16; mask <<= 1)
#pragma unroll
        for (int r = 0; r < 4; ++r) mx[r] = fmaxf(mx[r], __shfl_xor(mx[r], mask));

    float ssum[4];
#pragma unroll
    for (int r = 0; r < 4; ++r) {
        float mnew = fmaxf(mi[r], mx[r]);
        float alpha = __expf(mi[r] - mnew);
        mi[r] = mnew;
        float s = 0.f;
#pragma unroll
        for (int c = 0; c < 4; ++c) {
            float p = __expf(sc[c][r] - mnew);
            sc[c][r] = p; s += p;
        }
        ssum[r] = s;
        li[r] *= alpha;
#pragma unroll
        for (int t = 0; t < 4; ++t) o[t][r] *= alpha;
    }
#pragma unroll
    for (int mask = 1; mask < 16; mask <<= 1)
#pragma unroll
        for (int r = 0; r < 4; ++r) ssum[r] += __shfl_xor(ssum[r], mask);
#pragma unroll
    for (int r = 0; r < 4; ++r) li[r] += ssum[r];

    // P (C-layout) -> LDS -> A-layout fragments
#pragma unroll
    for (int c = 0; c < 4; ++c)
#pragma unroll
        for (int r = 0; r < 4; ++r) {
            bf16 pv = (bf16)sc[c][r];
            pb[(g * 4 + r) * PSTR + 16 * c + ln16] =
                __builtin_bit_cast(unsigned short, pv);
        }
    __asm__ volatile("s_waitcnt lgkmcnt(0)" ::: "memory");
    bf16x8 pf0 = *(const bf16x8*)(pb + ln16 * PSTR + g * 8);
    bf16x8 pf1 = *(const bf16x8*)(pb + ln16 * PSTR + 32 + g * 8);

#pragma unroll
    for (int t = 0; t < 4; ++t) {
        const bf16* vp = Vbh + (size_t)(16 * t + ln16) * SEQ + k0 + g * 8;
        bf16x8 bv0 = *(const bf16x8*)vp;
        bf16x8 bv1 = *(const bf16x8*)(vp + 32);
        o[t] = __builtin_amdgcn_mfma_f32_16x16x32_bf16(pf0, bv0, o[t], 0, 0, 0);
        o[t] = __builtin_amdgcn_mfma_f32_16x16x32_bf16(pf1, bv1, o[t], 0, 0, 0);
    }
}

__global__ __launch_bounds__(256) void attn_kernel(
    const bf16* __restrict__ Qh, const bf16* __restrict__ Kh,
    const bf16* __restrict__ Vt, bf16* __restrict__ O) {
    __shared__ alignas(16) unsigned short pbuf[4][16 * PSTR];

    const int wv = threadIdx.x >> 6;
    const int lane = threadIdx.x & 63;
    const int g = lane >> 4;
    const int ln16 = lane & 15;

    const int wid = blockIdx.x * 4 + wv;   // 0..4095
    const int bh = wid & 31;               // b*16+h
    const int qt = 127 - (wid >> 5);       // heavy tiles dispatched first
    const int qb = qt * 16;

    const bf16* Kbh = Kh + (size_t)bh * SEQ * DH;
    const bf16* Vbh = Vt + (size_t)bh * DH * SEQ;

    const bf16* qp = Qh + ((size_t)bh * SEQ + qb + ln16) * DH + g * 8;
    bf16x8 aq0 = *(const bf16x8*)qp;
    bf16x8 aq1 = *(const bf16x8*)(qp + 32);

    f32x4 o[4] = {};
    float mi[4], li[4];
#pragma unroll
    for (int r = 0; r < 4; ++r) { mi[r] = NEG_BIG; li[r] = 0.f; }

    unsigned short* pb = &pbuf[wv][0];
    const int nfull = qb >> 6;
    for (int kt = 0; kt < nfull; ++kt)
        attn_tile<false>(kt * 64, qb, g, ln16, aq0, aq1, Kbh, Vbh, pb, mi, li, o);
    attn_tile<true>(nfull * 64, qb, g, ln16, aq0, aq1, Kbh, Vbh, pb, mi, li, o);

    const int b = bh >> 4, h = bh & 15;
#pragma unroll
    for (int t = 0; t < 4; ++t)
#pragma unroll
        for (int r = 0; r < 4; ++r) {
            int token = b * SEQ + qb + g * 4 + r;
            float v = o[t][r] / li[r];
            O[(size_t)token * D_MODEL + h * DH + 16 * t + ln16] = (bf16)v;
        }
}

// ---------------------------------------------------------------------------
extern "C" void kernel_launch(void* const* d_in, const int* in_sizes, int n_in,
                              void* d_out, int out_size, void* d_ws, size_t ws_size,
                              hipStream_t stream) {
    const float* x     = (const float*)d_in[0];
    const float* W_dq  = (const float*)d_in[1];
    const float* W_uq  = (const float*)d_in[2];
    const float* q_g   = (const float*)d_in[3];
    const float* q_b   = (const float*)d_in[4];
    const float* W_dkv = (const float*)d_in[5];
    const float* W_ukv = (const float*)d_in[6];
    const float* kv_g  = (const float*)d_in[7];
    const float* kv_b  = (const float*)d_in[8];
    const float* W_o   = (const float*)d_in[9];

    char* ws = (char*)d_ws;
    size_t off = 0;
    bf16* x16    = (bf16*)(ws + off); off += (size_t)TOK * D_MODEL * 2;
    bf16* Wo16   = (bf16*)(ws + off); off += (size_t)D_MODEL * D_MODEL * 2;
    bf16* Wt_dq  = (bf16*)(ws + off); off += (size_t)PROJ * D_MODEL * 2;
    bf16* Wt_dkv = (bf16*)(ws + off); off += (size_t)PROJ * D_MODEL * 2;
    bf16* Wt_uq  = (bf16*)(ws + off); off += (size_t)D_MODEL * PROJ * 2;
    bf16* Wt_ukv = (bf16*)(ws + off); off += (size_t)(2 * D_MODEL) * PROJ * 2;
    bf16* cq     = (bf16*)(ws + off); off += (size_t)TOK * PROJ * 2;
    bf16* ckv    = (bf16*)(ws + off); off += (size_t)TOK * PROJ * 2;
    bf16* Qh     = (bf16*)(ws + off); off += (size_t)TOK * D_MODEL * 2;
    bf16* Kh     = (bf16*)(ws + off); off += (size_t)TOK * D_MODEL * 2;
    bf16* Vt     = (bf16*)(ws + off); off += (size_t)TOK * D_MODEL * 2;
    bf16* AT     = (bf16*)(ws + off); off += (size_t)TOK * D_MODEL * 2;

    cvt_kernel<<<2048, 256, 0, stream>>>(x, x16, TOK * D_MODEL);
    cvt_kernel<<<1024, 256, 0, stream>>>(W_o, Wo16, D_MODEL * D_MODEL);
    transpose_cvt_kernel<<<512, 256, 0, stream>>>(W_dq,  Wt_dq,  D_MODEL, PROJ);
    transpose_cvt_kernel<<<512, 256, 0, stream>>>(W_dkv, Wt_dkv, D_MODEL, PROJ);
    transpose_cvt_kernel<<<512, 256, 0, stream>>>(W_uq,  Wt_uq,  PROJ, D_MODEL);
    transpose_cvt_kernel<<<1024, 256, 0, stream>>>(W_ukv, Wt_ukv, PROJ, 2 * D_MODEL);

    gemm_ln_kernel<<<TOK / 16, 256, 0, stream>>>(x16, Wt_dq,  q_g,  q_b,  cq);
    gemm_ln_kernel<<<TOK / 16, 256, 0, stream>>>(x16, Wt_dkv, kv_g, kv_b, ckv);

    // Q = cq @ W_uq -> head-major Qh ; KV = ckv @ W_ukv -> Kh + transposed Vt
    gemm_kernel<1, bf16><<<dim3(TOK / 32, D_MODEL / 256), 256, 0, stream>>>(
        cq, Wt_uq, Qh, nullptr, TOK, D_MODEL, PROJ);
    gemm_kernel<2, bf16><<<dim3(TOK / 32, (2 * D_MODEL) / 256), 256, 0, stream>>>(
        ckv, Wt_ukv, Kh, Vt, TOK, 2 * D_MODEL, PROJ);

    attn_kernel<<<(BATCH * NH * (SEQ / 16)) / 4, 256, 0, stream>>>(Qh, Kh, Vt, AT);

    gemm_kernel<0, float><<<dim3(TOK / 32, D_MODEL / 256), 256, 0, stream>>>(
        AT, Wo16, (float*)d_out, nullptr, TOK, D_MODEL, D_MODEL);
}

// Round 4
// 362.091 us; speedup vs baseline: 1.0740x; 1.0728x over previous
//
#include <hip/hip_runtime.h>

typedef __bf16 bf16;
typedef __bf16 bf16x4 __attribute__((ext_vector_type(4)));
typedef __bf16 bf16x8 __attribute__((ext_vector_type(8)));
typedef float f32x4 __attribute__((ext_vector_type(4)));

#define D_MODEL 1024
#define PROJ    256
#define SEQ     2048
#define BATCH   2
#define TOK     4096   // BATCH*SEQ
#define NH      16
#define DH      64
#define NEG_BIG (-1e30f)
#define PSTR    72     // LDS P-tile stride (elements)

// ---------------------------------------------------------------------------
// DPP 16-lane row reductions (groups are contiguous 16-lane DPP rows).
template <int CTRL>
__device__ __forceinline__ float dppmov(float x) {
    int i = __builtin_bit_cast(int, x);
    i = __builtin_amdgcn_update_dpp(i, i, CTRL, 0xf, 0xf, false);
    return __builtin_bit_cast(float, i);
}
__device__ __forceinline__ float rowmax16(float v) {
    v = fmaxf(v, dppmov<0xB1>(v));    // quad_perm xor1
    v = fmaxf(v, dppmov<0x4E>(v));    // quad_perm xor2
    v = fmaxf(v, dppmov<0x141>(v));   // row_half_mirror (combines quads)
    v = fmaxf(v, dppmov<0x140>(v));   // row_mirror (combines halves)
    return v;
}
__device__ __forceinline__ float rowsum16(float v) {
    v += dppmov<0xB1>(v);
    v += dppmov<0x4E>(v);
    v += dppmov<0x141>(v);
    v += dppmov<0x140>(v);
    return v;
}

// ---------------------------------------------------------------------------
__global__ void cvt_kernel(const float* __restrict__ in, bf16* __restrict__ out, int n) {
    for (int i = blockIdx.x * blockDim.x + threadIdx.x; i < n;
         i += gridDim.x * blockDim.x)
        out[i] = (bf16)in[i];
}

// fp32 W[K][N] -> bf16 Wt[N][K] (n-major)
__global__ void transpose_cvt_kernel(const float* __restrict__ in, bf16* __restrict__ out,
                                     int K, int N) {
    int total = K * N;
    for (int i = blockIdx.x * blockDim.x + threadIdx.x; i < total;
         i += gridDim.x * blockDim.x) {
        int n = i / K;
        int k = i - n * K;
        out[i] = (bf16)in[k * N + n];
    }
}

// ---------------------------------------------------------------------------
// C_ln[4096][256] = LayerNorm_rowwise(A[4096][1024] @ W), Wt n-major.
__global__ __launch_bounds__(256) void gemm_ln_kernel(
    const bf16* __restrict__ A, const bf16* __restrict__ Wt,
    const float* __restrict__ gamma, const float* __restrict__ beta,
    bf16* __restrict__ out) {
    const int K = 1024;
    const int m0 = blockIdx.x * 16;
    const int wv = threadIdx.x >> 6;
    const int lane = threadIdx.x & 63;
    const int g = lane >> 4;
    const int ln16 = lane & 15;
    const int ncol0 = wv * 64;

    f32x4 acc[4] = {};
    const bf16* arow = A + (size_t)(m0 + ln16) * K + g * 8;
    for (int k0 = 0; k0 < K; k0 += 32) {
        bf16x8 a = *(const bf16x8*)(arow + k0);
#pragma unroll
        for (int t = 0; t < 4; ++t) {
            const bf16* bp = Wt + (size_t)(ncol0 + 16 * t + ln16) * K + k0 + g * 8;
            bf16x8 b = *(const bf16x8*)bp;
            acc[t] = __builtin_amdgcn_mfma_f32_16x16x32_bf16(a, b, acc[t], 0, 0, 0);
        }
    }

    float s1[4], s2[4];
#pragma unroll
    for (int r = 0; r < 4; ++r) {
        float a = 0.f, b = 0.f;
#pragma unroll
        for (int t = 0; t < 4; ++t) { float v = acc[t][r]; a += v; b += v * v; }
        s1[r] = rowsum16(a); s2[r] = rowsum16(b);
    }
    __shared__ float red1[4][16];
    __shared__ float red2[4][16];
    if (ln16 == 0) {
#pragma unroll
        for (int r = 0; r < 4; ++r) {
            red1[wv][g * 4 + r] = s1[r];
            red2[wv][g * 4 + r] = s2[r];
        }
    }
    __syncthreads();
#pragma unroll
    for (int r = 0; r < 4; ++r) {
        int row = g * 4 + r;
        float t1 = red1[0][row] + red1[1][row] + red1[2][row] + red1[3][row];
        float t2 = red2[0][row] + red2[1][row] + red2[2][row] + red2[3][row];
        float mu = t1 * (1.0f / 256.0f);
        float var = t2 * (1.0f / 256.0f) - mu * mu;
        float rs = rsqrtf(var + 1e-5f);
#pragma unroll
        for (int t = 0; t < 4; ++t) {
            int col = ncol0 + 16 * t + ln16;
            float v = (acc[t][r] - mu) * rs * gamma[col] + beta[col];
            out[(size_t)(m0 + row) * PROJ + col] = (bf16)v;
        }
    }
}

// ---------------------------------------------------------------------------
// Generic MFMA GEMM, A[M][K] row-major bf16, Bt[N][K] n-major bf16, fp32 acc.
// MODE 0: C[M][N] row-major, OutT.
// MODE 1: C = head-major bf16 [b*16+h][2048][64]   (Q up-proj)
// MODE 2: cols<1024 -> C = Kh head-major; cols>=1024 -> C2 = Vt [bh][64][2048]
template <int MODE, typename OutT>
__global__ __launch_bounds__(256) void gemm_kernel(
    const bf16* __restrict__ A, const bf16* __restrict__ Bt,
    OutT* __restrict__ C, bf16* __restrict__ C2, int M, int N, int K) {
    const int m0 = blockIdx.x * 32;
    const int n0 = blockIdx.y * 256 + (threadIdx.x >> 6) * 64;
    const int lane = threadIdx.x & 63;
    const int g = lane >> 4;
    const int ln16 = lane & 15;

    f32x4 acc[2][4] = {};
    const bf16* a0 = A + (size_t)(m0 + ln16) * K + g * 8;
    const bf16* a1 = a0 + (size_t)16 * K;
    for (int k0 = 0; k0 < K; k0 += 32) {
        bf16x8 A0 = *(const bf16x8*)(a0 + k0);
        bf16x8 A1 = *(const bf16x8*)(a1 + k0);
#pragma unroll
        for (int t = 0; t < 4; ++t) {
            const bf16* bp = Bt + (size_t)(n0 + 16 * t + ln16) * K + k0 + g * 8;
            bf16x8 b = *(const bf16x8*)bp;
            acc[0][t] = __builtin_amdgcn_mfma_f32_16x16x32_bf16(A0, b, acc[0][t], 0, 0, 0);
            acc[1][t] = __builtin_amdgcn_mfma_f32_16x16x32_bf16(A1, b, acc[1][t], 0, 0, 0);
        }
    }
#pragma unroll
    for (int s = 0; s < 2; ++s)
#pragma unroll
        for (int t = 0; t < 4; ++t) {
            const int col = n0 + 16 * t + ln16;
            const int tok0 = m0 + 16 * s + g * 4;
            if (MODE == 2 && col >= 1024) {
                int cc = col - 1024;
                int h = cc >> 6, d = cc & 63;
                int b = tok0 >> 11, sq = tok0 & 2047;
                bf16x4 pk;
#pragma unroll
                for (int r = 0; r < 4; ++r) pk[r] = (bf16)acc[s][t][r];
                *(bf16x4*)(C2 + ((size_t)((b * 16 + h) * 64 + d) * SEQ + sq)) = pk;
            } else {
#pragma unroll
                for (int r = 0; r < 4; ++r) {
                    int row = tok0 + r;
                    float v = acc[s][t][r];
                    if (MODE == 0) {
                        C[(size_t)row * N + col] = (OutT)v;
                    } else {
                        int h = col >> 6, d = col & 63;
                        int b = row >> 11, sq = row & 2047;
                        C[((size_t)((b * 16 + h) * 2048 + sq)) * 64 + d] = (OutT)v;
                    }
                }
            }
        }
}

// ---------------------------------------------------------------------------
// Flash attention, one wave = 16 q-rows, k-tile = 64. DPP softmax reductions.
template <bool MASKED>
__device__ __forceinline__ void attn_tile(
    int k0, int qb, int g, int ln16,
    bf16x8 aq0, bf16x8 aq1,
    const bf16* __restrict__ Kbh, const bf16* __restrict__ Vbh,
    unsigned short* __restrict__ pb,
    float* mi, float* li, f32x4* o) {
    f32x4 sc[4];
#pragma unroll
    for (int c = 0; c < 4; ++c) {
        const bf16* kp = Kbh + (size_t)(k0 + 16 * c + ln16) * DH + g * 8;
        bf16x8 b0 = *(const bf16x8*)kp;
        bf16x8 b1 = *(const bf16x8*)(kp + 32);
        f32x4 z = {};
        z = __builtin_amdgcn_mfma_f32_16x16x32_bf16(aq0, b0, z, 0, 0, 0);
        z = __builtin_amdgcn_mfma_f32_16x16x32_bf16(aq1, b1, z, 0, 0, 0);
        sc[c] = z;
    }

    // V fragment loads issued early — latency hides under softmax
    bf16x8 bv0[4], bv1[4];
#pragma unroll
    for (int t = 0; t < 4; ++t) {
        const bf16* vp = Vbh + (size_t)(16 * t + ln16) * SEQ + k0 + g * 8;
        bv0[t] = *(const bf16x8*)vp;
        bv1[t] = *(const bf16x8*)(vp + 32);
    }

    float mx[4];
#pragma unroll
    for (int r = 0; r < 4; ++r) {
#pragma unroll
        for (int c = 0; c < 4; ++c) {
            float v = sc[c][r] * 0.125f;
            if (MASKED) {
                int qrow = qb + g * 4 + r;
                int col = k0 + 16 * c + ln16;
                if (col > qrow) v = NEG_BIG;
            }
            sc[c][r] = v;
        }
        float m = fmaxf(fmaxf(sc[0][r], sc[1][r]), fmaxf(sc[2][r], sc[3][r]));
        mx[r] = rowmax16(m);
    }

#pragma unroll
    for (int r = 0; r < 4; ++r) {
        float mnew = fmaxf(mi[r], mx[r]);
        float alpha = __expf(mi[r] - mnew);
        mi[r] = mnew;
        float s = 0.f;
#pragma unroll
        for (int c = 0; c < 4; ++c) {
            float p = __expf(sc[c][r] - mnew);
            sc[c][r] = p; s += p;
        }
        li[r] = li[r] * alpha + rowsum16(s);
#pragma unroll
        for (int t = 0; t < 4; ++t) o[t][r] *= alpha;
    }

    // P (C-layout) -> LDS -> A-layout fragments
#pragma unroll
    for (int c = 0; c < 4; ++c)
#pragma unroll
        for (int r = 0; r < 4; ++r) {
            bf16 pv = (bf16)sc[c][r];
            pb[(g * 4 + r) * PSTR + 16 * c + ln16] =
                __builtin_bit_cast(unsigned short, pv);
        }
    __asm__ volatile("s_waitcnt lgkmcnt(0)" ::: "memory");
    bf16x8 pf0 = *(const bf16x8*)(pb + ln16 * PSTR + g * 8);
    bf16x8 pf1 = *(const bf16x8*)(pb + ln16 * PSTR + 32 + g * 8);

#pragma unroll
    for (int t = 0; t < 4; ++t) {
        o[t] = __builtin_amdgcn_mfma_f32_16x16x32_bf16(pf0, bv0[t], o[t], 0, 0, 0);
        o[t] = __builtin_amdgcn_mfma_f32_16x16x32_bf16(pf1, bv1[t], o[t], 0, 0, 0);
    }
}

__global__ __launch_bounds__(256) void attn_kernel(
    const bf16* __restrict__ Qh, const bf16* __restrict__ Kh,
    const bf16* __restrict__ Vt, bf16* __restrict__ O) {
    __shared__ alignas(16) unsigned short pbuf[4][16 * PSTR];

    const int wv = threadIdx.x >> 6;
    const int lane = threadIdx.x & 63;
    const int g = lane >> 4;
    const int ln16 = lane & 15;

    const int wid = blockIdx.x * 4 + wv;
    const int bh = wid & 31;
    const int qt = 127 - (wid >> 5);       // heavy tiles first
    const int qb = qt * 16;

    const bf16* Kbh = Kh + (size_t)bh * SEQ * DH;
    const bf16* Vbh = Vt + (size_t)bh * DH * SEQ;

    const bf16* qp = Qh + ((size_t)bh * SEQ + qb + ln16) * DH + g * 8;
    bf16x8 aq0 = *(const bf16x8*)qp;
    bf16x8 aq1 = *(const bf16x8*)(qp + 32);

    f32x4 o[4] = {};
    float mi[4], li[4];
#pragma unroll
    for (int r = 0; r < 4; ++r) { mi[r] = NEG_BIG; li[r] = 0.f; }

    unsigned short* pb = &pbuf[wv][0];
    const int nfull = qb >> 6;
    for (int kt = 0; kt < nfull; ++kt)
        attn_tile<false>(kt * 64, qb, g, ln16, aq0, aq1, Kbh, Vbh, pb, mi, li, o);
    attn_tile<true>(nfull * 64, qb, g, ln16, aq0, aq1, Kbh, Vbh, pb, mi, li, o);

    const int b = bh >> 4, h = bh & 15;
#pragma unroll
    for (int t = 0; t < 4; ++t)
#pragma unroll
        for (int r = 0; r < 4; ++r) {
            int token = b * SEQ + qb + g * 4 + r;
            float v = o[t][r] / li[r];
            O[(size_t)token * D_MODEL + h * DH + 16 * t + ln16] = (bf16)v;
        }
}

// ---------------------------------------------------------------------------
extern "C" void kernel_launch(void* const* d_in, const int* in_sizes, int n_in,
                              void* d_out, int out_size, void* d_ws, size_t ws_size,
                              hipStream_t stream) {
    const float* x     = (const float*)d_in[0];
    const float* W_dq  = (const float*)d_in[1];
    const float* W_uq  = (const float*)d_in[2];
    const float* q_g   = (const float*)d_in[3];
    const float* q_b   = (const float*)d_in[4];
    const float* W_dkv = (const float*)d_in[5];
    const float* W_ukv = (const float*)d_in[6];
    const float* kv_g  = (const float*)d_in[7];
    const float* kv_b  = (const float*)d_in[8];
    const float* W_o   = (const float*)d_in[9];

    char* ws = (char*)d_ws;
    size_t off = 0;
    bf16* x16    = (bf16*)(ws + off); off += (size_t)TOK * D_MODEL * 2;
    bf16* Wo16   = (bf16*)(ws + off); off += (size_t)D_MODEL * D_MODEL * 2;
    bf16* Wt_dq  = (bf16*)(ws + off); off += (size_t)PROJ * D_MODEL * 2;
    bf16* Wt_dkv = (bf16*)(ws + off); off += (size_t)PROJ * D_MODEL * 2;
    bf16* Wt_uq  = (bf16*)(ws + off); off += (size_t)D_MODEL * PROJ * 2;
    bf16* Wt_ukv = (bf16*)(ws + off); off += (size_t)(2 * D_MODEL) * PROJ * 2;
    bf16* cq     = (bf16*)(ws + off); off += (size_t)TOK * PROJ * 2;
    bf16* ckv    = (bf16*)(ws + off); off += (size_t)TOK * PROJ * 2;
    bf16* Qh     = (bf16*)(ws + off); off += (size_t)TOK * D_MODEL * 2;
    bf16* Kh     = (bf16*)(ws + off); off += (size_t)TOK * D_MODEL * 2;
    bf16* Vt     = (bf16*)(ws + off); off += (size_t)TOK * D_MODEL * 2;
    bf16* AT     = (bf16*)(ws + off); off += (size_t)TOK * D_MODEL * 2;

    cvt_kernel<<<2048, 256, 0, stream>>>(x, x16, TOK * D_MODEL);
    cvt_kernel<<<1024, 256, 0, stream>>>(W_o, Wo16, D_MODEL * D_MODEL);
    transpose_cvt_kernel<<<512, 256, 0, stream>>>(W_dq,  Wt_dq,  D_MODEL, PROJ);
    transpose_cvt_kernel<<<512, 256, 0, stream>>>(W_dkv, Wt_dkv, D_MODEL, PROJ);
    transpose_cvt_kernel<<<512, 256, 0, stream>>>(W_uq,  Wt_uq,  PROJ, D_MODEL);
    transpose_cvt_kernel<<<1024, 256, 0, stream>>>(W_ukv, Wt_ukv, PROJ, 2 * D_MODEL);

    gemm_ln_kernel<<<TOK / 16, 256, 0, stream>>>(x16, Wt_dq,  q_g,  q_b,  cq);
    gemm_ln_kernel<<<TOK / 16, 256, 0, stream>>>(x16, Wt_dkv, kv_g, kv_b, ckv);

    gemm_kernel<1, bf16><<<dim3(TOK / 32, D_MODEL / 256), 256, 0, stream>>>(
        cq, Wt_uq, Qh, nullptr, TOK, D_MODEL, PROJ);
    gemm_kernel<2, bf16><<<dim3(TOK / 32, (2 * D_MODEL) / 256), 256, 0, stream>>>(
        ckv, Wt_ukv, Kh, Vt, TOK, 2 * D_MODEL, PROJ);

    attn_kernel<<<(BATCH * NH * (SEQ / 16)) / 4, 256, 0, stream>>>(Qh, Kh, Vt, AT);

    gemm_kernel<0, float><<<dim3(TOK / 32, D_MODEL / 256), 256, 0, stream>>>(
        AT, Wo16, (float*)d_out, nullptr, TOK, D_MODEL, D_MODEL);
}

// Round 5
// 324.249 us; speedup vs baseline: 1.1993x; 1.1167x over previous
//
#include <hip/hip_runtime.h>

typedef __bf16 bf16;
typedef __bf16 bf16x4 __attribute__((ext_vector_type(4)));
typedef __bf16 bf16x8 __attribute__((ext_vector_type(8)));
typedef float f32x4 __attribute__((ext_vector_type(4)));

#define D_MODEL 1024
#define PROJ    256
#define SEQ     2048
#define BATCH   2
#define TOK     4096   // BATCH*SEQ
#define NH      16
#define DH      64
#define NEG_BIG (-1e30f)
#define PSTR    72     // LDS P-tile stride (elements)

// ---------------------------------------------------------------------------
// DPP 16-lane row reductions (groups are contiguous 16-lane DPP rows).
template <int CTRL>
__device__ __forceinline__ float dppmov(float x) {
    int i = __builtin_bit_cast(int, x);
    i = __builtin_amdgcn_update_dpp(i, i, CTRL, 0xf, 0xf, false);
    return __builtin_bit_cast(float, i);
}
__device__ __forceinline__ float rowmax16(float v) {
    v = fmaxf(v, dppmov<0xB1>(v));
    v = fmaxf(v, dppmov<0x4E>(v));
    v = fmaxf(v, dppmov<0x141>(v));
    v = fmaxf(v, dppmov<0x140>(v));
    return v;
}
__device__ __forceinline__ float rowsum16(float v) {
    v += dppmov<0xB1>(v);
    v += dppmov<0x4E>(v);
    v += dppmov<0x141>(v);
    v += dppmov<0x140>(v);
    return v;
}

// ---------------------------------------------------------------------------
// One kernel for all weight prep: W_o cvt + 4 transposes (fp32 -> bf16 n-major).
__global__ void prep_weights_kernel(
    const float* __restrict__ W_o,  const float* __restrict__ W_dq,
    const float* __restrict__ W_dkv, const float* __restrict__ W_uq,
    const float* __restrict__ W_ukv,
    bf16* __restrict__ Wo16, bf16* __restrict__ Wt_dq, bf16* __restrict__ Wt_dkv,
    bf16* __restrict__ Wt_uq, bf16* __restrict__ Wt_ukv) {
    const int R0 = 1048576;          // W_o: 1024x1024 straight cvt
    const int R1 = R0 + 262144;      // W_dq^T  : Wt[256][1024]
    const int R2 = R1 + 262144;      // W_dkv^T : Wt[256][1024]
    const int R3 = R2 + 262144;      // W_uq^T  : Wt[1024][256]
    const int R4 = R3 + 524288;      // W_ukv^T : Wt[2048][256]
    for (int i = blockIdx.x * blockDim.x + threadIdx.x; i < R4;
         i += gridDim.x * blockDim.x) {
        if (i < R0) {
            Wo16[i] = (bf16)W_o[i];
        } else if (i < R1) {
            int j = i - R0, n = j >> 10, k = j & 1023;       // K=1024,N=256
            Wt_dq[j] = (bf16)W_dq[k * 256 + n];
        } else if (i < R2) {
            int j = i - R1, n = j >> 10, k = j & 1023;
            Wt_dkv[j] = (bf16)W_dkv[k * 256 + n];
        } else if (i < R3) {
            int j = i - R2, n = j >> 8, k = j & 255;         // K=256,N=1024
            Wt_uq[j] = (bf16)W_uq[k * 1024 + n];
        } else {
            int j = i - R3, n = j >> 8, k = j & 255;         // K=256,N=2048
            Wt_ukv[j] = (bf16)W_ukv[k * 2048 + n];
        }
    }
}

// ---------------------------------------------------------------------------
// Dual LN-GEMM: blockIdx.y=0 -> cq=LN(x@W_dq), =1 -> ckv=LN(x@W_dkv).
// Reads x directly as fp32 (cvt fused).
__global__ __launch_bounds__(256) void gemm_ln_kernel(
    const float* __restrict__ x,
    const bf16* __restrict__ Wt_q, const bf16* __restrict__ Wt_kv,
    const float* __restrict__ q_g, const float* __restrict__ q_b,
    const float* __restrict__ kv_g, const float* __restrict__ kv_b,
    bf16* __restrict__ cq, bf16* __restrict__ ckv) {
    const int K = 1024;
    const bf16* Wt = blockIdx.y ? Wt_kv : Wt_q;
    const float* gamma = blockIdx.y ? kv_g : q_g;
    const float* beta  = blockIdx.y ? kv_b : q_b;
    bf16* out = blockIdx.y ? ckv : cq;

    const int m0 = blockIdx.x * 16;
    const int wv = threadIdx.x >> 6;
    const int lane = threadIdx.x & 63;
    const int g = lane >> 4;
    const int ln16 = lane & 15;
    const int ncol0 = wv * 64;

    f32x4 acc[4] = {};
    const float* arow = x + (size_t)(m0 + ln16) * K + g * 8;
    for (int k0 = 0; k0 < K; k0 += 32) {
        f32x4 f0 = *(const f32x4*)(arow + k0);
        f32x4 f1 = *(const f32x4*)(arow + k0 + 4);
        bf16x8 a;
#pragma unroll
        for (int j = 0; j < 4; ++j) { a[j] = (bf16)f0[j]; a[4 + j] = (bf16)f1[j]; }
#pragma unroll
        for (int t = 0; t < 4; ++t) {
            const bf16* bp = Wt + (size_t)(ncol0 + 16 * t + ln16) * K + k0 + g * 8;
            bf16x8 b = *(const bf16x8*)bp;
            acc[t] = __builtin_amdgcn_mfma_f32_16x16x32_bf16(a, b, acc[t], 0, 0, 0);
        }
    }

    float s1[4], s2[4];
#pragma unroll
    for (int r = 0; r < 4; ++r) {
        float a = 0.f, b = 0.f;
#pragma unroll
        for (int t = 0; t < 4; ++t) { float v = acc[t][r]; a += v; b += v * v; }
        s1[r] = rowsum16(a); s2[r] = rowsum16(b);
    }
    __shared__ float red1[4][16];
    __shared__ float red2[4][16];
    if (ln16 == 0) {
#pragma unroll
        for (int r = 0; r < 4; ++r) {
            red1[wv][g * 4 + r] = s1[r];
            red2[wv][g * 4 + r] = s2[r];
        }
    }
    __syncthreads();
#pragma unroll
    for (int r = 0; r < 4; ++r) {
        int row = g * 4 + r;
        float t1 = red1[0][row] + red1[1][row] + red1[2][row] + red1[3][row];
        float t2 = red2[0][row] + red2[1][row] + red2[2][row] + red2[3][row];
        float mu = t1 * (1.0f / 256.0f);
        float var = t2 * (1.0f / 256.0f) - mu * mu;
        float rs = rsqrtf(var + 1e-5f);
#pragma unroll
        for (int t = 0; t < 4; ++t) {
            int col = ncol0 + 16 * t + ln16;
            float v = (acc[t][r] - mu) * rs * gamma[col] + beta[col];
            out[(size_t)(m0 + row) * PROJ + col] = (bf16)v;
        }
    }
}

// ---------------------------------------------------------------------------
// Generic MFMA GEMM, A[M][K] row-major bf16, Bt[N][K] n-major bf16, fp32 acc.
// MODE 0: C[M][N] row-major, OutT.
// MODE 1: C = head-major bf16 [b*16+h][2048][64]   (Q up-proj)
// MODE 2: cols<1024 -> C = Kh head-major; cols>=1024 -> C2 = Vt [bh][64][2048]
template <int MODE, typename OutT>
__global__ __launch_bounds__(256) void gemm_kernel(
    const bf16* __restrict__ A, const bf16* __restrict__ Bt,
    OutT* __restrict__ C, bf16* __restrict__ C2, int M, int N, int K) {
    const int m0 = blockIdx.x * 32;
    const int n0 = blockIdx.y * 256 + (threadIdx.x >> 6) * 64;
    const int lane = threadIdx.x & 63;
    const int g = lane >> 4;
    const int ln16 = lane & 15;

    f32x4 acc[2][4] = {};
    const bf16* a0 = A + (size_t)(m0 + ln16) * K + g * 8;
    const bf16* a1 = a0 + (size_t)16 * K;
    for (int k0 = 0; k0 < K; k0 += 32) {
        bf16x8 A0 = *(const bf16x8*)(a0 + k0);
        bf16x8 A1 = *(const bf16x8*)(a1 + k0);
#pragma unroll
        for (int t = 0; t < 4; ++t) {
            const bf16* bp = Bt + (size_t)(n0 + 16 * t + ln16) * K + k0 + g * 8;
            bf16x8 b = *(const bf16x8*)bp;
            acc[0][t] = __builtin_amdgcn_mfma_f32_16x16x32_bf16(A0, b, acc[0][t], 0, 0, 0);
            acc[1][t] = __builtin_amdgcn_mfma_f32_16x16x32_bf16(A1, b, acc[1][t], 0, 0, 0);
        }
    }
#pragma unroll
    for (int s = 0; s < 2; ++s)
#pragma unroll
        for (int t = 0; t < 4; ++t) {
            const int col = n0 + 16 * t + ln16;
            const int tok0 = m0 + 16 * s + g * 4;
            if (MODE == 2 && col >= 1024) {
                int cc = col - 1024;
                int h = cc >> 6, d = cc & 63;
                int b = tok0 >> 11, sq = tok0 & 2047;
                bf16x4 pk;
#pragma unroll
                for (int r = 0; r < 4; ++r) pk[r] = (bf16)acc[s][t][r];
                *(bf16x4*)(C2 + ((size_t)((b * 16 + h) * 64 + d) * SEQ + sq)) = pk;
            } else {
#pragma unroll
                for (int r = 0; r < 4; ++r) {
                    int row = tok0 + r;
                    float v = acc[s][t][r];
                    if (MODE == 0) {
                        C[(size_t)row * N + col] = (OutT)v;
                    } else {
                        int h = col >> 6, d = col & 63;
                        int b = row >> 11, sq = row & 2047;
                        C[((size_t)((b * 16 + h) * 2048 + sq)) * 64 + d] = (OutT)v;
                    }
                }
            }
        }
}

// ---------------------------------------------------------------------------
// Paired-tile flash attention. One wave = two q-tiles (light qt=p, heavy
// qt=127-p) of the same (b,h): perfectly balanced ~34 k-tiles per wave,
// shared K/V fragment loads, two independent softmax/PV chains for ILP.
__device__ __forceinline__ void load_kfrags(const bf16* __restrict__ Kbh, int k0,
                                            int g, int ln16, bf16x8* Kf) {
#pragma unroll
    for (int c = 0; c < 4; ++c) {
        const bf16* kp = Kbh + (size_t)(k0 + 16 * c + ln16) * DH + g * 8;
        Kf[2 * c]     = *(const bf16x8*)kp;
        Kf[2 * c + 1] = *(const bf16x8*)(kp + 32);
    }
}
__device__ __forceinline__ void load_vfrags(const bf16* __restrict__ Vbh, int k0,
                                            int g, int ln16, bf16x8* Vf) {
#pragma unroll
    for (int t = 0; t < 4; ++t) {
        const bf16* vp = Vbh + (size_t)(16 * t + ln16) * SEQ + k0 + g * 8;
        Vf[2 * t]     = *(const bf16x8*)vp;
        Vf[2 * t + 1] = *(const bf16x8*)(vp + 32);
    }
}

// phase1: QK^T, online softmax, write P tile to LDS (no waitcnt here)
__device__ __forceinline__ void qk_softmax(
    int k0, int qb, int g, int ln16,
    bf16x8 aq0, bf16x8 aq1, const bf16x8* Kf,
    unsigned short* __restrict__ pb, float* mi, float* li, f32x4* o) {
    f32x4 sc[4];
#pragma unroll
    for (int c = 0; c < 4; ++c) {
        f32x4 z = {};
        z = __builtin_amdgcn_mfma_f32_16x16x32_bf16(aq0, Kf[2 * c], z, 0, 0, 0);
        z = __builtin_amdgcn_mfma_f32_16x16x32_bf16(aq1, Kf[2 * c + 1], z, 0, 0, 0);
        sc[c] = z;
    }
    float mx[4];
#pragma unroll
    for (int r = 0; r < 4; ++r) {
        int qrow = qb + g * 4 + r;
#pragma unroll
        for (int c = 0; c < 4; ++c) {
            int col = k0 + 16 * c + ln16;
            float v = sc[c][r] * 0.125f;
            if (col > qrow) v = NEG_BIG;     // inert for full tiles
            sc[c][r] = v;
        }
        float m = fmaxf(fmaxf(sc[0][r], sc[1][r]), fmaxf(sc[2][r], sc[3][r]));
        mx[r] = rowmax16(m);
    }
#pragma unroll
    for (int r = 0; r < 4; ++r) {
        float mnew = fmaxf(mi[r], mx[r]);
        float alpha = __expf(mi[r] - mnew);
        mi[r] = mnew;
        float s = 0.f;
#pragma unroll
        for (int c = 0; c < 4; ++c) {
            float p = __expf(sc[c][r] - mnew);
            sc[c][r] = p; s += p;
        }
        li[r] = li[r] * alpha + rowsum16(s);
#pragma unroll
        for (int t = 0; t < 4; ++t) o[t][r] *= alpha;
    }
#pragma unroll
    for (int c = 0; c < 4; ++c)
#pragma unroll
        for (int r = 0; r < 4; ++r) {
            bf16 pv = (bf16)sc[c][r];
            pb[(g * 4 + r) * PSTR + 16 * c + ln16] =
                __builtin_bit_cast(unsigned short, pv);
        }
}

// phase2: read P tile as A-frags, PV accumulate
__device__ __forceinline__ void pv_accum(
    const unsigned short* __restrict__ pb, int g, int ln16,
    const bf16x8* Vf, f32x4* o) {
    bf16x8 pf0 = *(const bf16x8*)(pb + ln16 * PSTR + g * 8);
    bf16x8 pf1 = *(const bf16x8*)(pb + ln16 * PSTR + 32 + g * 8);
#pragma unroll
    for (int t = 0; t < 4; ++t) {
        o[t] = __builtin_amdgcn_mfma_f32_16x16x32_bf16(pf0, Vf[2 * t], o[t], 0, 0, 0);
        o[t] = __builtin_amdgcn_mfma_f32_16x16x32_bf16(pf1, Vf[2 * t + 1], o[t], 0, 0, 0);
    }
}

__global__ __launch_bounds__(256, 2) void attn_kernel(
    const bf16* __restrict__ Qh, const bf16* __restrict__ Kh,
    const bf16* __restrict__ Vt, bf16* __restrict__ O) {
    __shared__ alignas(16) unsigned short pbuf[4][2][16 * PSTR];

    const int wv = threadIdx.x >> 6;
    const int lane = threadIdx.x & 63;
    const int g = lane >> 4;
    const int ln16 = lane & 15;

    const int wid = blockIdx.x * 4 + wv;   // 0..2047
    const int bh = wid & 31;
    const int p  = wid >> 5;               // 0..63
    const int qbL = p * 16;                // light tile
    const int qbH = (127 - p) * 16;        // heavy tile
    const int lastL = p >> 2;              // boundary k-tile index
    const int lastH = (127 - p) >> 2;

    const bf16* Kbh = Kh + (size_t)bh * SEQ * DH;
    const bf16* Vbh = Vt + (size_t)bh * DH * SEQ;

    const bf16* qpL = Qh + ((size_t)bh * SEQ + qbL + ln16) * DH + g * 8;
    const bf16* qpH = Qh + ((size_t)bh * SEQ + qbH + ln16) * DH + g * 8;
    bf16x8 aqL0 = *(const bf16x8*)qpL, aqL1 = *(const bf16x8*)(qpL + 32);
    bf16x8 aqH0 = *(const bf16x8*)qpH, aqH1 = *(const bf16x8*)(qpH + 32);

    f32x4 oL[4] = {}, oH[4] = {};
    float miL[4], liL[4], miH[4], liH[4];
#pragma unroll
    for (int r = 0; r < 4; ++r) {
        miL[r] = NEG_BIG; liL[r] = 0.f;
        miH[r] = NEG_BIG; liH[r] = 0.f;
    }

    unsigned short* pbL = &pbuf[wv][0][0];
    unsigned short* pbH = &pbuf[wv][1][0];

    bf16x8 Kf[8], Kn[8], Vf[8];
    load_kfrags(Kbh, 0, g, ln16, Kf);

    for (int kt = 0; kt <= lastH; ++kt) {
        const int k0 = kt * 64;
        load_vfrags(Vbh, k0, g, ln16, Vf);           // consumed after softmax
        if (kt < lastH) load_kfrags(Kbh, k0 + 64, g, ln16, Kn);  // prefetch

        const bool actL = (kt <= lastL);
        if (actL) qk_softmax(k0, qbL, g, ln16, aqL0, aqL1, Kf, pbL, miL, liL, oL);
        qk_softmax(k0, qbH, g, ln16, aqH0, aqH1, Kf, pbH, miH, liH, oH);
        __asm__ volatile("s_waitcnt lgkmcnt(0)" ::: "memory");
        if (actL) pv_accum(pbL, g, ln16, Vf, oL);
        pv_accum(pbH, g, ln16, Vf, oH);

#pragma unroll
        for (int i = 0; i < 8; ++i) Kf[i] = Kn[i];
    }

    const int b = bh >> 4, h = bh & 15;
#pragma unroll
    for (int t = 0; t < 4; ++t)
#pragma unroll
        for (int r = 0; r < 4; ++r) {
            int tokL = b * SEQ + qbL + g * 4 + r;
            int tokH = b * SEQ + qbH + g * 4 + r;
            O[(size_t)tokL * D_MODEL + h * DH + 16 * t + ln16] = (bf16)(oL[t][r] / liL[r]);
            O[(size_t)tokH * D_MODEL + h * DH + 16 * t + ln16] = (bf16)(oH[t][r] / liH[r]);
        }
}

// ---------------------------------------------------------------------------
extern "C" void kernel_launch(void* const* d_in, const int* in_sizes, int n_in,
                              void* d_out, int out_size, void* d_ws, size_t ws_size,
                              hipStream_t stream) {
    const float* x     = (const float*)d_in[0];
    const float* W_dq  = (const float*)d_in[1];
    const float* W_uq  = (const float*)d_in[2];
    const float* q_g   = (const float*)d_in[3];
    const float* q_b   = (const float*)d_in[4];
    const float* W_dkv = (const float*)d_in[5];
    const float* W_ukv = (const float*)d_in[6];
    const float* kv_g  = (const float*)d_in[7];
    const float* kv_b  = (const float*)d_in[8];
    const float* W_o   = (const float*)d_in[9];

    char* ws = (char*)d_ws;
    size_t off = 0;
    bf16* Wo16   = (bf16*)(ws + off); off += (size_t)D_MODEL * D_MODEL * 2;
    bf16* Wt_dq  = (bf16*)(ws + off); off += (size_t)PROJ * D_MODEL * 2;
    bf16* Wt_dkv = (bf16*)(ws + off); off += (size_t)PROJ * D_MODEL * 2;
    bf16* Wt_uq  = (bf16*)(ws + off); off += (size_t)D_MODEL * PROJ * 2;
    bf16* Wt_ukv = (bf16*)(ws + off); off += (size_t)(2 * D_MODEL) * PROJ * 2;
    bf16* cq     = (bf16*)(ws + off); off += (size_t)TOK * PROJ * 2;
    bf16* ckv    = (bf16*)(ws + off); off += (size_t)TOK * PROJ * 2;
    bf16* Qh     = (bf16*)(ws + off); off += (size_t)TOK * D_MODEL * 2;
    bf16* Kh     = (bf16*)(ws + off); off += (size_t)TOK * D_MODEL * 2;
    bf16* Vt     = (bf16*)(ws + off); off += (size_t)TOK * D_MODEL * 2;
    bf16* AT     = (bf16*)(ws + off); off += (size_t)TOK * D_MODEL * 2;

    prep_weights_kernel<<<2048, 256, 0, stream>>>(
        W_o, W_dq, W_dkv, W_uq, W_ukv, Wo16, Wt_dq, Wt_dkv, Wt_uq, Wt_ukv);

    gemm_ln_kernel<<<dim3(TOK / 16, 2), 256, 0, stream>>>(
        x, Wt_dq, Wt_dkv, q_g, q_b, kv_g, kv_b, cq, ckv);

    gemm_kernel<1, bf16><<<dim3(TOK / 32, D_MODEL / 256), 256, 0, stream>>>(
        cq, Wt_uq, Qh, nullptr, TOK, D_MODEL, PROJ);
    gemm_kernel<2, bf16><<<dim3(TOK / 32, (2 * D_MODEL) / 256), 256, 0, stream>>>(
        ckv, Wt_ukv, Kh, Vt, TOK, 2 * D_MODEL, PROJ);

    attn_kernel<<<512, 256, 0, stream>>>(Qh, Kh, Vt, AT);

    gemm_kernel<0, float><<<dim3(TOK / 32, D_MODEL / 256), 256, 0, stream>>>(
        AT, Wo16, (float*)d_out, nullptr, TOK, D_MODEL, D_MODEL);
}